// Round 7
// baseline (380.150 us; speedup 1.0000x reference)
//
#include <hip/hip_runtime.h>
#include <math.h>

#define IMG 512
#define PLANES 96            // 32 N * 3 C
#define XS_W 54              // valid output columns per wave (64 lanes - 10 halo)
#define NXS 10               // ceil(512/54)
#define YS_H 128             // output rows per wave
#define NYS 4                // 512/128
#define WPB 4                // waves per block
#define NBLK ((PLANES * NXS * NYS) / WPB)   // 960 blocks
#define INV_NPIX (1.0 / 25165824.0)

// ws layout: float4 part[NBLK] (15360 B) — per-block partial sums, plain stores.

static __device__ __forceinline__ float rflf(float x) {
    return __int_as_float(__builtin_amdgcn_readfirstlane(__float_as_int(x)));
}

// DPP wave-wide lane shifts (VALU pipe). wave_shr:1 (0x138): lane i reads lane i-1.
// wave_shl:1 (0x130): lane i reads lane i+1. bound_ctrl: OOB lanes read 0 —
// consumed only by halo lanes that never emit.
static __device__ __forceinline__ float dpp_shr1(float x) {
    return __int_as_float(__builtin_amdgcn_mov_dpp(__float_as_int(x), 0x138, 0xF, 0xF, true));
}
static __device__ __forceinline__ float dpp_shl1(float x) {
    return __int_as_float(__builtin_amdgcn_mov_dpp(__float_as_int(x), 0x130, 0xF, 0xF, true));
}

// One row step, phase P = t % 11, buffer parity BSEL = t & 1 (caller-guaranteed).
// Depth-2 prefetch WITHOUT rotation: consume buffer[t&1] (row t), reload the
// SAME buffer with row t+2 (write-after-read inside one step; period-2
// self-contained live range — no cross-buffer moves, nothing for the RA to
// spill; R6's rotation produced 113 MB of scratch traffic).
// Vertical ring: slot (P+j+1)%11 += g[10-j]*H; j==10 overwrites the slot
// emitted last step (mul, no zeroing). Emit slot (P+1)%11.
// Arithmetic and accumulation order identical to the verified R4 kernel.
template<int P, int BSEL, bool EMIT>
__device__ __forceinline__ void row_step(
    int T, int y0, bool col_ok,
    const float* __restrict__ p1, const float* __restrict__ p2,
    float& xe1, float& xe2, float& xo1, float& xo2,
    const float (&g)[11],
    float (&A)[5][11], bool out_ok, float& sL, float& sC, float& sS)
{
    const int t = T + P;
    float& x1r = BSEL ? xo1 : xe1;                 // compile-time select
    float& x2r = BSEL ? xo2 : xe2;
    // ---- prefetch row t+2 (coalesced: lane = column; independent of x reads) ----
    const int gy2 = y0 - 3 + t;                    // gy of row t+2
    float nx1 = 0.f, nx2 = 0.f;
    if (col_ok && (unsigned)gy2 < IMG) {
        int off = gy2 * IMG;
        nx1 = p1[off];
        nx2 = p2[off];
    }
    // ---- horizontal window on row t: left chain materialized, right rolled ----
    const float x1 = x1r, x2 = x2r;
    float a4 = dpp_shr1(x1), b4 = dpp_shr1(x2);
    float a3 = dpp_shr1(a4), b3 = dpp_shr1(b4);
    float a2 = dpp_shr1(a3), b2r = dpp_shr1(b3);
    float a1 = dpp_shr1(a2), b1r = dpp_shr1(b2r);
    float a0 = dpp_shr1(a1), b0 = dpp_shr1(b1r);
    // j = 0
    float t1 = g[0] * a0, t2 = g[0] * b0;
    float H1 = t1, H2 = t2;
    float H11 = t1 * a0, H22 = t2 * b0, H12 = t1 * b0;
#define HACC(J, AJ, BJ)                                   \
    t1 = g[J] * (AJ); t2 = g[J] * (BJ);                   \
    H1 += t1; H2 += t2;                                   \
    H11 = fmaf(t1, (AJ), H11);                            \
    H22 = fmaf(t2, (BJ), H22);                            \
    H12 = fmaf(t1, (BJ), H12);
    HACC(1, a1, b1r)
    HACC(2, a2, b2r)
    HACC(3, a3, b3)
    HACC(4, a4, b4)
    HACC(5, x1, x2)
    float ar = dpp_shl1(x1), br = dpp_shl1(x2);
    HACC(6, ar, br)
    ar = dpp_shl1(ar); br = dpp_shl1(br);
    HACC(7, ar, br)
    ar = dpp_shl1(ar); br = dpp_shl1(br);
    HACC(8, ar, br)
    ar = dpp_shl1(ar); br = dpp_shl1(br);
    HACC(9, ar, br)
    ar = dpp_shl1(ar); br = dpp_shl1(br);
    HACC(10, ar, br)
#undef HACC
    // ---- vertical ring accumulate (static slot indices, t ≡ P mod 11) ----
    #pragma unroll
    for (int j = 0; j < 11; ++j) {
        const int s = (P + j + 1) % 11;
        float w = g[10 - j];
        if (j == 10) {                             // fresh slot (== P): overwrite
            A[0][s] = w * H1;
            A[1][s] = w * H2;
            A[2][s] = w * H11;
            A[3][s] = w * H22;
            A[4][s] = w * H12;
        } else {
            A[0][s] = fmaf(w, H1,  A[0][s]);
            A[1][s] = fmaf(w, H2,  A[1][s]);
            A[2][s] = fmaf(w, H11, A[2][s]);
            A[3][s] = fmaf(w, H22, A[3][s]);
            A[4][s] = fmaf(w, H12, A[4][s]);
        }
    }
    // ---- emit output row r = t-10 (slot (P+1)%11) ----
    if (EMIT) {
        const int es = (P + 1) % 11;
        float mu1 = A[0][es], mu2 = A[1][es];
        float x11 = A[2][es], x22 = A[3][es], x12 = A[4][es];
        float mu1s = mu1 * mu1, mu2s = mu2 * mu2, mu12 = mu1 * mu2;
        float v1 = x11 - mu1s, v2 = x22 - mu2s, v12 = x12 - mu12;
        float q1 = fabsf(v1), q2 = fabsf(v2);
        float q12 = sqrtf(q1 * q2);                // sqrt(a1)*sqrt(a2)
        const float C1 = 1e-4f, C2 = 9e-4f, C3 = 4.5e-4f;
        float eL = __fdividef(2.f * mu12 + C1, mu1s + mu2s + C1);
        float eC = __fdividef(2.f * q12 + C2, q1 + q2 + C2);
        float eS = __fdividef(v12 + C3, q12 + C3);
        if (out_ok) { sL += eL; sC += eC; sS += eS; }
    }
    // write back into the SAME parity buffer (next touched at step t+2)
    x1r = nx1; x2r = nx2;
}

#define RS(Tc, Pc, Bc, Ec) \
    row_step<Pc, Bc, Ec>(Tc, y0, col_ok, p1, p2, xe1, xe2, xo1, xo2, g, A, out_ok, sL, sC, sS)

__global__ __launch_bounds__(256, 4) void ssim_main(
    const float* __restrict__ img1, const float* __restrict__ img2,
    const float* __restrict__ win, float4* __restrict__ part)
{
    const int lane = threadIdx.x & 63;
    const int widx = threadIdx.x >> 6;
    const int wid  = blockIdx.x * WPB + widx;
    const int plane = wid / (NXS * NYS);
    const int rem   = wid % (NXS * NYS);
    const int ys = rem / NXS, xs = rem % NXS;
    const int x0 = xs * XS_W;
    const int y0 = ys * YS_H;
    const int col = x0 - 5 + lane;                 // this lane's image column
    const bool col_ok = (unsigned)col < IMG;
    const bool out_ok = (lane >= 5) && (lane <= 58) && col_ok;

    // separable 1-D Gaussian from diagonal of 2-D window (channel 0):
    // w2d[i][i] = g[i]^2 -> g[i] = sqrt(win[i*12]). Uniform -> SGPRs.
    float g[11];
    #pragma unroll
    for (int j = 0; j < 11; ++j) g[j] = rflf(sqrtf(win[j * 12]));

    const float* p1 = img1 + (size_t)plane * (IMG * IMG) + col;
    const float* p2 = img2 + (size_t)plane * (IMG * IMG) + col;

    // warm the pipeline: row t=0 (gy=y0-5) -> even buffer, t=1 (gy=y0-4) -> odd
    float xe1 = 0.f, xe2 = 0.f, xo1 = 0.f, xo2 = 0.f;
    {
        int gy = y0 - 5;
        if (col_ok && (unsigned)gy < IMG) { xe1 = p1[gy * IMG]; xe2 = p2[gy * IMG]; }
        gy = y0 - 4;
        if (col_ok && (unsigned)gy < IMG) { xo1 = p1[gy * IMG]; xo2 = p2[gy * IMG]; }
    }

    float A[5][11];
    #pragma unroll
    for (int q = 0; q < 5; ++q)
        #pragma unroll
        for (int s = 0; s < 11; ++s) A[q][s] = 0.f;

    float sL = 0.f, sC = 0.f, sS = 0.f;

    // warm-up t = 0..10 (T=0 even: BSEL = P&1); t=10 emits row 0
    RS(0, 0, 0, false);
    RS(0, 1, 1, false);
    RS(0, 2, 0, false);
    RS(0, 3, 1, false);
    RS(0, 4, 0, false);
    RS(0, 5, 1, false);
    RS(0, 6, 0, false);
    RS(0, 7, 1, false);
    RS(0, 8, 0, false);
    RS(0, 9, 1, false);
    RS(0, 10, 0, true);

    #pragma unroll 1
    for (int T = 11; T < 121; T += 22) {           // t = 11..120, all emit
        // first 11 steps: T odd -> BSEL = (P+1)&1
        RS(T, 0, 1, true);
        RS(T, 1, 0, true);
        RS(T, 2, 1, true);
        RS(T, 3, 0, true);
        RS(T, 4, 1, true);
        RS(T, 5, 0, true);
        RS(T, 6, 1, true);
        RS(T, 7, 0, true);
        RS(T, 8, 1, true);
        RS(T, 9, 0, true);
        RS(T, 10, 1, true);
        // second 11 steps: T+11 even -> BSEL = P&1
        RS(T + 11, 0, 0, true);
        RS(T + 11, 1, 1, true);
        RS(T + 11, 2, 0, true);
        RS(T + 11, 3, 1, true);
        RS(T + 11, 4, 0, true);
        RS(T + 11, 5, 1, true);
        RS(T + 11, 6, 0, true);
        RS(T + 11, 7, 1, true);
        RS(T + 11, 8, 0, true);
        RS(T + 11, 9, 1, true);
        RS(T + 11, 10, 0, true);
    }
    // tail: t = 121..131 (T=121 odd -> BSEL=(P+1)&1)
    RS(121, 0, 1, true);
    RS(121, 1, 0, true);
    RS(121, 2, 1, true);
    RS(121, 3, 0, true);
    RS(121, 4, 1, true);
    RS(121, 5, 0, true);
    RS(121, 6, 1, true);
    RS(121, 7, 0, true);
    RS(121, 8, 1, true);
    RS(121, 9, 0, true);
    RS(121, 10, 1, true);
    // tail: t = 132..137 (T=132 even -> BSEL=P&1)
    RS(132, 0, 0, true);
    RS(132, 1, 1, true);
    RS(132, 2, 0, true);
    RS(132, 3, 1, true);
    RS(132, 4, 0, true);
    RS(132, 5, 1, true);

    // ---- wave reduction, then block reduction via tiny LDS, one plain store ----
    #pragma unroll
    for (int off = 32; off > 0; off >>= 1) {
        sL += __shfl_down(sL, off, 64);
        sC += __shfl_down(sC, off, 64);
        sS += __shfl_down(sS, off, 64);
    }
    __shared__ float red[WPB][4];
    if (lane == 0) { red[widx][0] = sL; red[widx][1] = sC; red[widx][2] = sS; }
    __syncthreads();
    if (threadIdx.x == 0) {
        float L = 0.f, C = 0.f, S = 0.f;
        #pragma unroll
        for (int w = 0; w < WPB; ++w) { L += red[w][0]; C += red[w][1]; S += red[w][2]; }
        part[blockIdx.x] = make_float4(L, C, S, 0.f);
    }
}

__global__ void ssim_fin(const float4* __restrict__ part, float* __restrict__ out) {
    const int t = threadIdx.x;
    double L = 0.0, C = 0.0, S = 0.0;
    for (int i = t; i < NBLK; i += 256) {
        float4 p = part[i];
        L += (double)p.x; C += (double)p.y; S += (double)p.z;
    }
    __shared__ double red[256][3];
    red[t][0] = L; red[t][1] = C; red[t][2] = S;
    __syncthreads();
    for (int s = 128; s > 0; s >>= 1) {
        if (t < s) {
            red[t][0] += red[t + s][0];
            red[t][1] += red[t + s][1];
            red[t][2] += red[t + s][2];
        }
        __syncthreads();
    }
    if (t < 3) out[t] = (float)(red[0][t] * INV_NPIX);
}

extern "C" void kernel_launch(void* const* d_in, const int* in_sizes, int n_in,
                              void* d_out, int out_size, void* d_ws, size_t ws_size,
                              hipStream_t stream) {
    const float* img1 = (const float*)d_in[0];
    const float* img2 = (const float*)d_in[1];
    const float* win  = (const float*)d_in[2];
    float* out = (float*)d_out;
    float4* part = (float4*)d_ws;                  // NBLK * 16 B = 15360 B

    ssim_main<<<NBLK, 64 * WPB, 0, stream>>>(img1, img2, win, part);
    ssim_fin<<<1, 256, 0, stream>>>(part, out);
}

// Round 8
// 312.732 us; speedup vs baseline: 1.2156x; 1.2156x over previous
//
#include <hip/hip_runtime.h>
#include <math.h>

#define IMG 512
#define PLANES 96            // 32 N * 3 C
#define XS_W 54              // valid output columns per wave (64 lanes - 10 halo)
#define NXS 10               // ceil(512/54)
#define YS_H 64              // output rows per wave
#define NYS 8                // 512/64
#define WPB 4                // waves per block
#define NBLK ((PLANES * NXS * NYS) / WPB)   // 1920 blocks
#define INV_NPIX (1.0 / 25165824.0)

// ws layout: float4 part[NBLK] (30720 B) — per-block partial sums, plain stores.

static __device__ __forceinline__ float rflf(float x) {
    return __int_as_float(__builtin_amdgcn_readfirstlane(__float_as_int(x)));
}

// DPP wave-wide lane shifts (VALU pipe). wave_shr:1 (0x138): lane i reads lane i-1.
// wave_shl:1 (0x130): lane i reads lane i+1. bound_ctrl: OOB lanes read 0 —
// consumed only by halo lanes that never emit.
static __device__ __forceinline__ float dpp_shr1(float x) {
    return __int_as_float(__builtin_amdgcn_mov_dpp(__float_as_int(x), 0x138, 0xF, 0xF, true));
}
static __device__ __forceinline__ float dpp_shl1(float x) {
    return __int_as_float(__builtin_amdgcn_mov_dpp(__float_as_int(x), 0x130, 0xF, 0xF, true));
}

// One row step, phase P = t % 11, buffer parity BSEL = t & 1 (caller-guaranteed).
// Depth-2 prefetch, parity double-buffer: consume buffer[t&1] (row t), reload
// the SAME buffer with row t+2. Branchless row handling: row index clamped
// (address always valid, uniform -> SADDR), value zeroed by multiplying with
// mask in {0.0f,1.0f} — exact (r*1.0==r bitwise, r*0.0==+0 for finite r>=0).
// Vertical ring: slot (P+j+1)%11 += g[10-j]*H; j==10 overwrites the slot
// emitted last step (mul, no zeroing). Emit slot (P+1)%11.
// H/V/emit arithmetic identical to the verified R4 kernel (absmax 0 preserved).
template<int P, int BSEL, bool EMIT>
__device__ __forceinline__ void row_step(
    int T, int y0s,
    const float* __restrict__ b1, const float* __restrict__ b2,  // uniform plane bases
    unsigned colc, float colokf,
    float& xe1, float& xe2, float& xo1, float& xo2,
    const float (&g)[11],
    float (&A)[5][11], bool out_ok, float& sL, float& sC, float& sS)
{
    const int t = T + P;
    float& x1r = BSEL ? xo1 : xe1;                 // compile-time select
    float& x2r = BSEL ? xo2 : xe2;
    // ---- prefetch row t+2 (uniform clamped row -> scalar base + lane offset) ----
    const int gy = y0s - 3 + t;                    // image row of t+2 (uniform)
    const int gyc = gy < 0 ? 0 : (gy > IMG - 1 ? IMG - 1 : gy);
    const float rowf = ((unsigned)gy < IMG) ? 1.f : 0.f;
    const unsigned roff = (unsigned)(gyc * IMG);
    float r1 = b1[roff + colc];
    float r2 = b2[roff + colc];
    const float mask = colokf * rowf;
    float nx1 = r1 * mask;
    float nx2 = r2 * mask;
    // ---- horizontal window on row t: left chain materialized, right rolled ----
    const float x1 = x1r, x2 = x2r;
    float a4 = dpp_shr1(x1), b4 = dpp_shr1(x2);
    float a3 = dpp_shr1(a4), b3 = dpp_shr1(b4);
    float a2 = dpp_shr1(a3), b2r = dpp_shr1(b3);
    float a1 = dpp_shr1(a2), b1r = dpp_shr1(b2r);
    float a0 = dpp_shr1(a1), b0 = dpp_shr1(b1r);
    // j = 0
    float t1 = g[0] * a0, t2 = g[0] * b0;
    float H1 = t1, H2 = t2;
    float H11 = t1 * a0, H22 = t2 * b0, H12 = t1 * b0;
#define HACC(J, AJ, BJ)                                   \
    t1 = g[J] * (AJ); t2 = g[J] * (BJ);                   \
    H1 += t1; H2 += t2;                                   \
    H11 = fmaf(t1, (AJ), H11);                            \
    H22 = fmaf(t2, (BJ), H22);                            \
    H12 = fmaf(t1, (BJ), H12);
    HACC(1, a1, b1r)
    HACC(2, a2, b2r)
    HACC(3, a3, b3)
    HACC(4, a4, b4)
    HACC(5, x1, x2)
    float ar = dpp_shl1(x1), br = dpp_shl1(x2);
    HACC(6, ar, br)
    ar = dpp_shl1(ar); br = dpp_shl1(br);
    HACC(7, ar, br)
    ar = dpp_shl1(ar); br = dpp_shl1(br);
    HACC(8, ar, br)
    ar = dpp_shl1(ar); br = dpp_shl1(br);
    HACC(9, ar, br)
    ar = dpp_shl1(ar); br = dpp_shl1(br);
    HACC(10, ar, br)
#undef HACC
    // ---- vertical ring accumulate (static slot indices, t ≡ P mod 11) ----
    #pragma unroll
    for (int j = 0; j < 11; ++j) {
        const int s = (P + j + 1) % 11;
        float w = g[10 - j];
        if (j == 10) {                             // fresh slot (== P): overwrite
            A[0][s] = w * H1;
            A[1][s] = w * H2;
            A[2][s] = w * H11;
            A[3][s] = w * H22;
            A[4][s] = w * H12;
        } else {
            A[0][s] = fmaf(w, H1,  A[0][s]);
            A[1][s] = fmaf(w, H2,  A[1][s]);
            A[2][s] = fmaf(w, H11, A[2][s]);
            A[3][s] = fmaf(w, H22, A[3][s]);
            A[4][s] = fmaf(w, H12, A[4][s]);
        }
    }
    // ---- emit output row r = t-10 (slot (P+1)%11) ----
    if (EMIT) {
        const int es = (P + 1) % 11;
        float mu1 = A[0][es], mu2 = A[1][es];
        float x11 = A[2][es], x22 = A[3][es], x12 = A[4][es];
        float mu1s = mu1 * mu1, mu2s = mu2 * mu2, mu12 = mu1 * mu2;
        float v1 = x11 - mu1s, v2 = x22 - mu2s, v12 = x12 - mu12;
        float q1 = fabsf(v1), q2 = fabsf(v2);
        float q12 = sqrtf(q1 * q2);                // sqrt(a1)*sqrt(a2)
        const float C1 = 1e-4f, C2 = 9e-4f, C3 = 4.5e-4f;
        float eL = __fdividef(2.f * mu12 + C1, mu1s + mu2s + C1);
        float eC = __fdividef(2.f * q12 + C2, q1 + q2 + C2);
        float eS = __fdividef(v12 + C3, q12 + C3);
        if (out_ok) { sL += eL; sC += eC; sS += eS; }
    }
    // write back into the SAME parity buffer (next touched at step t+2)
    x1r = nx1; x2r = nx2;
}

#define RS(Tc, Pc, Bc, Ec) \
    row_step<Pc, Bc, Ec>(Tc, y0s, b1, b2, colc, colokf, xe1, xe2, xo1, xo2, g, A, out_ok, sL, sC, sS)

__global__ __launch_bounds__(256, 3) void ssim_main(
    const float* __restrict__ img1, const float* __restrict__ img2,
    const float* __restrict__ win, float4* __restrict__ part)
{
    const int lane = threadIdx.x & 63;
    const int widx = threadIdx.x >> 6;
    const int wid  = blockIdx.x * WPB + widx;
    const int plane = wid / (NXS * NYS);
    const int rem   = wid % (NXS * NYS);
    const int ys = rem / NXS, xs = rem % NXS;
    const int x0 = xs * XS_W;
    const int y0 = ys * YS_H;
    const int col = x0 - 5 + lane;                 // this lane's image column
    const bool col_ok = (unsigned)col < IMG;
    const bool out_ok = (lane >= 5) && (lane <= 58) && col_ok;
    const unsigned colc = (unsigned)(col < 0 ? 0 : (col > IMG - 1 ? IMG - 1 : col));
    const float colokf = col_ok ? 1.f : 0.f;

    // wave-uniform scalars -> SGPRs
    const int y0s = __builtin_amdgcn_readfirstlane(y0);
    const int plane_u = __builtin_amdgcn_readfirstlane(plane);
    const float* b1 = img1 + (size_t)plane_u * (IMG * IMG);
    const float* b2 = img2 + (size_t)plane_u * (IMG * IMG);

    // separable 1-D Gaussian from diagonal of 2-D window (channel 0):
    // w2d[i][i] = g[i]^2 -> g[i] = sqrt(win[i*12]). Uniform -> SGPRs.
    float g[11];
    #pragma unroll
    for (int j = 0; j < 11; ++j) g[j] = rflf(sqrtf(win[j * 12]));

    // warm the pipeline: row t=0 (gy=y0-5) -> even buffer, t=1 (gy=y0-4) -> odd
    float xe1, xe2, xo1, xo2;
    {
        int gy = y0s - 5;
        int gyc = gy < 0 ? 0 : gy;                 // y0s-5 <= 443, no upper clamp needed
        float rowf = ((unsigned)gy < IMG) ? 1.f : 0.f;
        float m = colokf * rowf;
        unsigned roff = (unsigned)(gyc * IMG);
        xe1 = b1[roff + colc] * m;
        xe2 = b2[roff + colc] * m;
        gy = y0s - 4;
        gyc = gy < 0 ? 0 : gy;
        rowf = ((unsigned)gy < IMG) ? 1.f : 0.f;
        m = colokf * rowf;
        roff = (unsigned)(gyc * IMG);
        xo1 = b1[roff + colc] * m;
        xo2 = b2[roff + colc] * m;
    }

    float A[5][11];
    #pragma unroll
    for (int q = 0; q < 5; ++q)
        #pragma unroll
        for (int s = 0; s < 11; ++s) A[q][s] = 0.f;

    float sL = 0.f, sC = 0.f, sS = 0.f;

    // warm-up t = 0..10 (T=0 even: BSEL = P&1); t=10 emits row 0
    RS(0, 0, 0, false);
    RS(0, 1, 1, false);
    RS(0, 2, 0, false);
    RS(0, 3, 1, false);
    RS(0, 4, 0, false);
    RS(0, 5, 1, false);
    RS(0, 6, 0, false);
    RS(0, 7, 1, false);
    RS(0, 8, 0, false);
    RS(0, 9, 1, false);
    RS(0, 10, 0, true);

    #pragma unroll 1
    for (int T = 11; T < 55; T += 22) {            // t = 11..54, all emit
        // first 11 steps: T odd -> BSEL = (P+1)&1
        RS(T, 0, 1, true);
        RS(T, 1, 0, true);
        RS(T, 2, 1, true);
        RS(T, 3, 0, true);
        RS(T, 4, 1, true);
        RS(T, 5, 0, true);
        RS(T, 6, 1, true);
        RS(T, 7, 0, true);
        RS(T, 8, 1, true);
        RS(T, 9, 0, true);
        RS(T, 10, 1, true);
        // second 11 steps: T+11 even -> BSEL = P&1
        RS(T + 11, 0, 0, true);
        RS(T + 11, 1, 1, true);
        RS(T + 11, 2, 0, true);
        RS(T + 11, 3, 1, true);
        RS(T + 11, 4, 0, true);
        RS(T + 11, 5, 1, true);
        RS(T + 11, 6, 0, true);
        RS(T + 11, 7, 1, true);
        RS(T + 11, 8, 0, true);
        RS(T + 11, 9, 1, true);
        RS(T + 11, 10, 0, true);
    }
    // tail: t = 55..65 (T=55 odd -> BSEL=(P+1)&1)
    RS(55, 0, 1, true);
    RS(55, 1, 0, true);
    RS(55, 2, 1, true);
    RS(55, 3, 0, true);
    RS(55, 4, 1, true);
    RS(55, 5, 0, true);
    RS(55, 6, 1, true);
    RS(55, 7, 0, true);
    RS(55, 8, 1, true);
    RS(55, 9, 0, true);
    RS(55, 10, 1, true);
    // tail: t = 66..73 (T=66 even -> BSEL=P&1)
    RS(66, 0, 0, true);
    RS(66, 1, 1, true);
    RS(66, 2, 0, true);
    RS(66, 3, 1, true);
    RS(66, 4, 0, true);
    RS(66, 5, 1, true);
    RS(66, 6, 0, true);
    RS(66, 7, 1, true);

    // ---- wave reduction, then block reduction via tiny LDS, one plain store ----
    #pragma unroll
    for (int off = 32; off > 0; off >>= 1) {
        sL += __shfl_down(sL, off, 64);
        sC += __shfl_down(sC, off, 64);
        sS += __shfl_down(sS, off, 64);
    }
    __shared__ float red[WPB][4];
    if (lane == 0) { red[widx][0] = sL; red[widx][1] = sC; red[widx][2] = sS; }
    __syncthreads();
    if (threadIdx.x == 0) {
        float L = 0.f, C = 0.f, S = 0.f;
        #pragma unroll
        for (int w = 0; w < WPB; ++w) { L += red[w][0]; C += red[w][1]; S += red[w][2]; }
        part[blockIdx.x] = make_float4(L, C, S, 0.f);
    }
}

__global__ void ssim_fin(const float4* __restrict__ part, float* __restrict__ out) {
    const int t = threadIdx.x;
    double L = 0.0, C = 0.0, S = 0.0;
    for (int i = t; i < NBLK; i += 256) {
        float4 p = part[i];
        L += (double)p.x; C += (double)p.y; S += (double)p.z;
    }
    __shared__ double red[256][3];
    red[t][0] = L; red[t][1] = C; red[t][2] = S;
    __syncthreads();
    for (int s = 128; s > 0; s >>= 1) {
        if (t < s) {
            red[t][0] += red[t + s][0];
            red[t][1] += red[t + s][1];
            red[t][2] += red[t + s][2];
        }
        __syncthreads();
    }
    if (t < 3) out[t] = (float)(red[0][t] * INV_NPIX);
}

extern "C" void kernel_launch(void* const* d_in, const int* in_sizes, int n_in,
                              void* d_out, int out_size, void* d_ws, size_t ws_size,
                              hipStream_t stream) {
    const float* img1 = (const float*)d_in[0];
    const float* img2 = (const float*)d_in[1];
    const float* win  = (const float*)d_in[2];
    float* out = (float*)d_out;
    float4* part = (float4*)d_ws;                  // NBLK * 16 B = 30720 B

    ssim_main<<<NBLK, 64 * WPB, 0, stream>>>(img1, img2, win, part);
    ssim_fin<<<1, 256, 0, stream>>>(part, out);
}